// Round 1
// baseline (57.347 us; speedup 1.0000x reference)
//
#include <hip/hip_runtime.h>
#include <math.h>

// LegendreBasis: out[b, nb] = prod_d P_{e[d,nb]}(clip(actions[b,d], -1, 1))
// actions: [B, D] f32; exponents: [D, NB] i32; out: [B, NB] f32.
// Write-bound: out is ~260 MB. Strategy: coalesced output-major loop,
// Legendre table per row staged in LDS, per-basis factor "program" packed
// into one uint32 (<=4 nonzero exponents since sum <= rank=4).

#define THREADS 256
#define TILE 16          // rows staged per phase
#define ROWSTRIDE 41     // 8 dims * 5 orders + 1 pad (bank-conflict break)

__global__ __launch_bounds__(THREADS, 8) void legendre_fast(
    const float* __restrict__ actions,
    const int* __restrict__ exps,
    float* __restrict__ out,
    int B, int D, int NB, int rank, int rows_per_block)
{
    __shared__ unsigned prog[1024];          // packed factor program per basis
    __shared__ float Pl[TILE * ROWSTRIDE];   // Legendre values for TILE rows

    const int t = threadIdx.x;

    // ---- build packed factor program (once per block) ----
    // factor index = d*5 + e  (fits 6 bits, <= 39); slot 0 -> Pl[...,0] == 1.0
    for (int nb = t; nb < NB; nb += THREADS) {
        unsigned pk = 0;
        int shift = 0;
        for (int d = 0; d < D; ++d) {
            int e = exps[d * NB + nb];
            if (e > 0) {
                pk |= (unsigned)(d * 5 + e) << shift;
                shift += 6;
            }
        }
        prog[nb] = pk;
    }
    // (visibility of prog covered by the first __syncthreads below)

    int r0 = blockIdx.x * rows_per_block;
    int rend = r0 + rows_per_block;
    if (rend > B) rend = B;

    for (; r0 < rend; r0 += TILE) {
        int nrows = rend - r0;
        if (nrows > TILE) nrows = TILE;

        // ---- stage Legendre table for this row tile ----
        if (t < nrows * D) {
            int rl = t / D;
            int d  = t - rl * D;
            float x = actions[(long long)(r0 + rl) * D + d];
            x = fminf(fmaxf(x, -1.0f), 1.0f);
            float* Pr = &Pl[rl * ROWSTRIDE + d * 5];
            float p0 = 1.0f, p1 = x;
            Pr[0] = 1.0f;
            if (rank >= 1) Pr[1] = x;
            for (int n = 2; n <= rank; ++n) {
                float fn = (float)n;
                float pn = ((2.0f * fn - 1.0f) / fn) * x * p1
                         - ((fn - 1.0f) / fn) * p0;
                Pr[n] = pn;
                p0 = p1;
                p1 = pn;
            }
        }
        __syncthreads();

        // ---- coalesced output loop over nrows*NB contiguous elements ----
        int total_o = nrows * NB;
        long long gbase = (long long)r0 * NB;
        int rl = t / NB;          // fine for any NB (runtime div once)
        int nb = t - rl * NB;
        for (int o = t; o < total_o; o += THREADS) {
            unsigned pk = prog[nb];
            const float* Pr = &Pl[rl * ROWSTRIDE];
            float f0 = Pr[pk & 63u];
            float f1 = Pr[(pk >> 6) & 63u];
            float f2 = Pr[(pk >> 12) & 63u];
            float f3 = Pr[(pk >> 18) & 63u];
            out[gbase + o] = (f0 * f1) * (f2 * f3);
            nb += THREADS;
            while (nb >= NB) { nb -= NB; ++rl; }
        }
        __syncthreads();  // protect Pl before next phase overwrites it
    }
}

// Generic fallback: one thread per output element, rolling recurrence
// (no register-array indexing). Correct for any D/rank/NB.
__global__ void legendre_generic(
    const float* __restrict__ actions,
    const int* __restrict__ exps,
    float* __restrict__ out,
    long long total, int D, int NB)
{
    long long stride = (long long)gridDim.x * blockDim.x;
    for (long long i = (long long)blockIdx.x * blockDim.x + threadIdx.x;
         i < total; i += stride) {
        int nb = (int)(i % NB);
        long long row = i / NB;
        float prod = 1.0f;
        for (int d = 0; d < D; ++d) {
            int e = exps[d * NB + nb];
            float x = actions[row * D + d];
            x = fminf(fmaxf(x, -1.0f), 1.0f);
            float p0 = 1.0f, p1 = x;
            float p = (e == 0) ? 1.0f : x;
            for (int n = 2; n <= e; ++n) {
                float fn = (float)n;
                float pn = ((2.0f * fn - 1.0f) / fn) * x * p1
                         - ((fn - 1.0f) / fn) * p0;
                p0 = p1;
                p1 = pn;
                p = pn;
            }
            prod *= p;
        }
        out[i] = prod;
    }
}

extern "C" void kernel_launch(void* const* d_in, const int* in_sizes, int n_in,
                              void* d_out, int out_size, void* d_ws, size_t ws_size,
                              hipStream_t stream) {
    const float* actions = (const float*)d_in[0];
    const int* exps = (const int*)d_in[1];
    float* out = (float*)d_out;

    long long in0 = in_sizes[0];   // B*D
    long long in1 = in_sizes[1];   // D*NB
    long long osz = out_size;      // B*NB

    // D^2 = in0*in1/out_size
    int D = (int)(sqrt((double)in0 * (double)in1 / (double)osz) + 0.5);
    if (D < 1) D = 1;
    int NB = (int)(in1 / D);
    int B = (int)(in0 / D);

    // rank from C(D+r, r) == NB
    int rank = -1;
    {
        long long c = 1;  // C(D+0, 0)
        for (int r = 0; r <= 32; ++r) {
            if (c == (long long)NB) { rank = r; break; }
            c = c * (D + r + 1) / (r + 1);
            if (c > (long long)NB) break;
        }
    }

    bool fast = (rank >= 0 && rank <= 4 && D >= 1 && D <= 8 &&
                 NB >= 1 && NB <= 1024 && (long long)B * NB == osz &&
                 (long long)B * D == in0);

    if (fast) {
        int nblk = 2048;
        if (B < nblk) nblk = B;
        int rpb = (B + nblk - 1) / nblk;
        legendre_fast<<<nblk, THREADS, 0, stream>>>(
            actions, exps, out, B, D, NB, rank, rpb);
    } else {
        long long total = osz;
        long long want = (total + 255) / 256;
        int nblk = (want > 8192) ? 8192 : (int)(want > 0 ? want : 1);
        legendre_generic<<<nblk, 256, 0, stream>>>(
            actions, exps, out, total, D, NB);
    }
}

// Round 3
// 55.418 us; speedup vs baseline: 1.0348x; 1.0348x over previous
//
#include <hip/hip_runtime.h>
#include <math.h>

// LegendreBasis: out[b, nb] = prod_d P_{e[d,nb]}(clip(actions[b,d], -1, 1))
// actions: [B, D] f32; exponents: [D, NB] i32; out: [B, NB] f32.
// Write-bound (~260 MB out). Strategy: one block per 32-row tile, Legendre
// table in LDS, packed per-basis factor "program" (<=4 factors, 6b LDS idx
// each) in LDS with a bit-rotated layout so 4-elem-chunk reads are
// lane-consecutive, float4 non-temporal stores (native ext_vector type).

#define THREADS 256
#define TILE 32          // rows per block
#define ROWSTRIDE 41     // 8 dims * 5 orders + 1 pad

typedef float f32x4 __attribute__((ext_vector_type(4)));

__global__ __launch_bounds__(THREADS, 8) void legendre_fast(
    const float* __restrict__ actions,
    const int* __restrict__ exps,
    float* __restrict__ out,
    int B, int D, int NB, int rank, int stepq, int stepr)
{
    __shared__ unsigned prog[512];           // swizzled: prog[(nb&3)*128 + nb/4]
    __shared__ float Pl[TILE * ROWSTRIDE];   // Legendre values for TILE rows

    const int t = threadIdx.x;
    const int r0 = blockIdx.x * TILE;

    // ---- build packed factor program ----
    // factor index = d*5 + e (6 bits); slot 0 -> Pl[...,0] == 1.0 (pad)
    for (int nb = t; nb < NB; nb += THREADS) {
        unsigned pk = 0;
        int shift = 0;
        for (int d = 0; d < D; ++d) {
            int e = exps[d * NB + nb];
            if (e > 0) {
                pk |= (unsigned)(d * 5 + e) << shift;
                shift += 6;
            }
        }
        prog[((nb & 3) << 7) | (nb >> 2)] = pk;
    }

    // ---- stage Legendre table for this row tile (256 = 32 rows x 8 dims) ----
    if (t < TILE * D) {
        int rl = t / D;
        int d  = t - rl * D;
        float x = actions[(long long)(r0 + rl) * D + d];
        x = fminf(fmaxf(x, -1.0f), 1.0f);
        float* Pr = &Pl[rl * ROWSTRIDE + d * 5];
        float p0 = 1.0f, p1 = x;
        Pr[0] = 1.0f;
        if (rank >= 1) Pr[1] = x;
        for (int n = 2; n <= rank; ++n) {
            float fn = (float)n;
            float pn = ((2.0f * fn - 1.0f) / fn) * x * p1
                     - ((fn - 1.0f) / fn) * p0;
            Pr[n] = pn;
            p0 = p1;
            p1 = pn;
        }
    }
    __syncthreads();

    // ---- output: 4 consecutive elements per thread, float4 nt stores ----
    const int nchunks = (TILE * NB) >> 2;            // (TILE*NB)%4==0 guaranteed
    f32x4* __restrict__ o4 = (f32x4*)(out + (long long)r0 * NB);

    int o0 = t << 2;
    int rl = o0 / NB;            // once per thread
    int nb = o0 - rl * NB;

    for (int c = t; c < nchunks; c += THREADS) {
        int nbi = nb, rli = rl;
        float res[4];
#pragma unroll
        for (int i = 0; i < 4; ++i) {
            unsigned pk = prog[((nbi & 3) << 7) | (nbi >> 2)];
            const float* Pr = &Pl[rli * ROWSTRIDE];
            float f0 = Pr[pk & 63u];
            float f1 = Pr[(pk >> 6) & 63u];
            float f2 = Pr[(pk >> 12) & 63u];
            float f3 = Pr[(pk >> 18) & 63u];
            res[i] = (f0 * f1) * (f2 * f3);
            ++nbi;
            if (nbi == NB) { nbi = 0; ++rli; }
        }
        f32x4 v;
        v.x = res[0]; v.y = res[1]; v.z = res[2]; v.w = res[3];
        __builtin_nontemporal_store(v, o4 + c);

        nb += stepr;             // advance by THREADS*4 elements mod NB
        rl += stepq;
        if (nb >= NB) { nb -= NB; ++rl; }
    }
}

// Generic fallback: one thread per output element, rolling recurrence.
__global__ void legendre_generic(
    const float* __restrict__ actions,
    const int* __restrict__ exps,
    float* __restrict__ out,
    long long total, int D, int NB)
{
    long long stride = (long long)gridDim.x * blockDim.x;
    for (long long i = (long long)blockIdx.x * blockDim.x + threadIdx.x;
         i < total; i += stride) {
        int nb = (int)(i % NB);
        long long row = i / NB;
        float prod = 1.0f;
        for (int d = 0; d < D; ++d) {
            int e = exps[d * NB + nb];
            float x = actions[row * D + d];
            x = fminf(fmaxf(x, -1.0f), 1.0f);
            float p0 = 1.0f, p1 = x;
            float p = (e == 0) ? 1.0f : x;
            for (int n = 2; n <= e; ++n) {
                float fn = (float)n;
                float pn = ((2.0f * fn - 1.0f) / fn) * x * p1
                         - ((fn - 1.0f) / fn) * p0;
                p0 = p1;
                p1 = pn;
                p = pn;
            }
            prod *= p;
        }
        out[i] = prod;
    }
}

extern "C" void kernel_launch(void* const* d_in, const int* in_sizes, int n_in,
                              void* d_out, int out_size, void* d_ws, size_t ws_size,
                              hipStream_t stream) {
    const float* actions = (const float*)d_in[0];
    const int* exps = (const int*)d_in[1];
    float* out = (float*)d_out;

    long long in0 = in_sizes[0];   // B*D
    long long in1 = in_sizes[1];   // D*NB
    long long osz = out_size;      // B*NB

    // D^2 = in0*in1/out_size
    int D = (int)(sqrt((double)in0 * (double)in1 / (double)osz) + 0.5);
    if (D < 1) D = 1;
    int NB = (int)(in1 / D);
    int B = (int)(in0 / D);

    // rank from C(D+r, r) == NB
    int rank = -1;
    {
        long long c = 1;
        for (int r = 0; r <= 32; ++r) {
            if (c == (long long)NB) { rank = r; break; }
            c = c * (D + r + 1) / (r + 1);
            if (c > (long long)NB) break;
        }
    }

    bool fast = (rank >= 0 && rank <= 4 && D >= 1 && D <= 8 &&
                 NB >= 1 && NB <= 512 &&
                 (long long)B * NB == osz && (long long)B * D == in0 &&
                 (B % TILE) == 0 && ((TILE * NB) % 4) == 0);

    if (fast) {
        int nblk = B / TILE;
        int stepq = (THREADS * 4) / NB;
        int stepr = (THREADS * 4) % NB;
        legendre_fast<<<nblk, THREADS, 0, stream>>>(
            actions, exps, out, B, D, NB, rank, stepq, stepr);
    } else {
        long long total = osz;
        long long want = (total + 255) / 256;
        int nblk = (want > 8192) ? 8192 : (int)(want > 0 ? want : 1);
        legendre_generic<<<nblk, 256, 0, stream>>>(
            actions, exps, out, total, D, NB);
    }
}

// Round 4
// 46.902 us; speedup vs baseline: 1.2227x; 1.1816x over previous
//
#include <hip/hip_runtime.h>
#include <math.h>

// LegendreBasis: out[b, nb] = prod_d P_{e[d,nb]}(clip(actions[b,d], -1, 1))
// B=131072, D=8, NB=495, rank=4. Write-bound (~260 MB out), but the naive
// gather costs 5 LDS reads/element -> DS-pipe-bound (~48us). Restructure:
// basis = U-monomial(dims 0-3) x V-monomial(dims 4-7), 70 monomials each
// (deg<=4). Per 32-row tile: per-row U/V tables (built with fully-static
// unrolled loops) + per-chunk u64 program (periodic, 495 entries). Inner
// loop: 1 ds_read_b64 + 8 ds_read_b32 + 4 muls per 4 elements.

#define THREADS 256
#define TILE 32
#define RSTRIDE 142   // per-row: U[0..70] then V at +71 (71 floats each, padded)

typedef float f32x4 __attribute__((ext_vector_type(4)));

__device__ __forceinline__ int c2i(int n){ return (n < 2) ? 0 : (n*(n-1))>>1; }
__device__ __forceinline__ int c3i(int n){ return (n < 3) ? 0 : (n*(n-1)*(n-2))/6; }
__device__ __forceinline__ int c4i(int n){ return (n < 4) ? 0 : (n*(n-1)*(n-2)*(n-3))/24; }

// rank of (a,b,c,d), sum<=4, in nested-loop order (d fastest). Range [0,70).
__device__ __forceinline__ int rank4(int a, int b, int c, int d) {
    return (70 - c4i(8-a)) + (c3i(7-a) - c3i(7-a-b))
         + (c2i(6-a-b) - c2i(6-a-b-c)) + d;
}

__global__ __launch_bounds__(THREADS, 4) void legendre_fast(
    const float* __restrict__ actions,
    const int* __restrict__ exps,
    float* __restrict__ out)
{
    __shared__ unsigned long long cprog[495]; // per-chunk: 4x14b (a|b<<7) + wrap flags
    __shared__ float UV[TILE * RSTRIDE];      // per-row U (71) + V (71)
    __shared__ unsigned short tmp16[496];     // per-nb a|b<<7

    const int t = threadIdx.x;
    const int r0 = blockIdx.x * TILE;

    // ---- phase 1: per-basis (a_idx, b_idx) from exponents ----
    for (int nb = t; nb < 495; nb += THREADS) {
        int e0 = exps[0*495+nb], e1 = exps[1*495+nb];
        int e2 = exps[2*495+nb], e3 = exps[3*495+nb];
        int e4 = exps[4*495+nb], e5 = exps[5*495+nb];
        int e6 = exps[6*495+nb], e7 = exps[7*495+nb];
        int ai = rank4(e0, e1, e2, e3);
        int bi = rank4(e4, e5, e6, e7);
        tmp16[nb] = (unsigned short)(ai | (bi << 7));
    }
    __syncthreads();

    // ---- phase 2a (wave 0): build U/V monomial tables, one (row,half)/thread ----
    if (t < 64) {
        int row = t >> 1, half = t & 1;
        f32x4 xv = *(const f32x4*)(actions + (long long)(r0 + row) * 8 + half * 4);
        float P[4][5];
#pragma unroll
        for (int d = 0; d < 4; ++d) {
            float x = fminf(fmaxf(xv[d], -1.0f), 1.0f);
            P[d][0] = 1.0f; P[d][1] = x;
#pragma unroll
            for (int n = 2; n <= 4; ++n) {
                float fn = (float)n;
                P[d][n] = ((2.0f*fn - 1.0f)/fn) * x * P[d][n-1]
                        - ((fn - 1.0f)/fn) * P[d][n-2];
            }
        }
        float* W = &UV[row * RSTRIDE + half * 71];
        int cnt = 0;
#pragma unroll
        for (int a = 0; a <= 4; ++a) { float q0 = P[0][a];
#pragma unroll
            for (int b = 0; b <= 4-a; ++b) { float q1 = q0 * P[1][b];
#pragma unroll
                for (int c = 0; c <= 4-a-b; ++c) { float q2 = q1 * P[2][c];
#pragma unroll
                    for (int d = 0; d <= 4-a-b-c; ++d) { W[cnt++] = q2 * P[3][d]; }
                }
            }
        }
    } else {
        // ---- phase 2b (threads 64..255): per-chunk program, period 495 ----
        for (int j = t - 64; j < 495; j += THREADS - 64) {
            int f = 4 * j;                       // <= 1976
            int nb0 = f;
            nb0 -= (nb0 >= 990) ? 990 : 0;
            nb0 -= (nb0 >= 495) ? 495 : 0;
            unsigned p0 = tmp16[nb0];
            int n1 = nb0 + 1; unsigned w1 = (n1 >= 495); n1 -= w1 ? 495 : 0;
            int n2 = nb0 + 2; unsigned w2 = (n2 >= 495); n2 -= w2 ? 495 : 0;
            int n3 = nb0 + 3; unsigned w3 = (n3 >= 495); n3 -= w3 ? 495 : 0;
            unsigned p1 = tmp16[n1], p2 = tmp16[n2], p3 = tmp16[n3];
            unsigned lo = p0 | (p1 << 14) | (w1 << 28) | (w2 << 29) | (w3 << 30);
            unsigned hi = p2 | (p3 << 14);
            cprog[j] = ((unsigned long long)hi << 32) | lo;
        }
    }
    __syncthreads();

    // ---- main loop: 4 elements/chunk, 1 b64 + 8 b32 LDS reads, f32x4 store ----
    const int nchunks = TILE * 495 / 4;          // 3960
    f32x4* __restrict__ o4 = (f32x4*)(out + (long long)r0 * 495);

    int m = t;                                   // chunk index mod 495 (t < 495)
    int f0 = 4 * t;                              // flat element index (<=1020)
    int rl = (f0 >= 495) + (f0 >= 990);
    int nb0 = f0 - rl * 495;
    int rowoff = rl * RSTRIDE;

    for (int c = t; c < nchunks; c += THREADS) {
        unsigned long long e = cprog[m];
        unsigned lo = (unsigned)e, hi = (unsigned)(e >> 32);
        float r0v, r1v, r2v, r3v;
        {
            int a = lo & 127, b = (lo >> 7) & 127;
            r0v = UV[rowoff + a] * UV[rowoff + 71 + b];
        }
        {
            int a = (lo >> 14) & 127, b = (lo >> 21) & 127;
            int ro = rowoff + (((lo >> 28) & 1) ? RSTRIDE : 0);
            r1v = UV[ro + a] * UV[ro + 71 + b];
        }
        {
            int a = hi & 127, b = (hi >> 7) & 127;
            int ro = rowoff + (((lo >> 29) & 1) ? RSTRIDE : 0);
            r2v = UV[ro + a] * UV[ro + 71 + b];
        }
        {
            int a = (hi >> 14) & 127, b = (hi >> 21) & 127;
            int ro = rowoff + (((lo >> 30) & 1) ? RSTRIDE : 0);
            r3v = UV[ro + a] * UV[ro + 71 + b];
        }
        f32x4 v; v.x = r0v; v.y = r1v; v.z = r2v; v.w = r3v;
        o4[c] = v;

        m += THREADS; if (m >= 495) m -= 495;
        nb0 += 34; rowoff += 2 * RSTRIDE;        // flat += 1024 = 2*495 + 34
        if (nb0 >= 495) { nb0 -= 495; rowoff += RSTRIDE; }
    }
}

// Generic fallback: one thread per output element, rolling recurrence.
__global__ void legendre_generic(
    const float* __restrict__ actions,
    const int* __restrict__ exps,
    float* __restrict__ out,
    long long total, int D, int NB)
{
    long long stride = (long long)gridDim.x * blockDim.x;
    for (long long i = (long long)blockIdx.x * blockDim.x + threadIdx.x;
         i < total; i += stride) {
        int nb = (int)(i % NB);
        long long row = i / NB;
        float prod = 1.0f;
        for (int d = 0; d < D; ++d) {
            int e = exps[d * NB + nb];
            float x = actions[row * D + d];
            x = fminf(fmaxf(x, -1.0f), 1.0f);
            float p0 = 1.0f, p1 = x;
            float p = (e == 0) ? 1.0f : x;
            for (int n = 2; n <= e; ++n) {
                float fn = (float)n;
                float pn = ((2.0f*fn - 1.0f)/fn) * x * p1 - ((fn - 1.0f)/fn) * p0;
                p0 = p1; p1 = pn; p = pn;
            }
            prod *= p;
        }
        out[i] = prod;
    }
}

extern "C" void kernel_launch(void* const* d_in, const int* in_sizes, int n_in,
                              void* d_out, int out_size, void* d_ws, size_t ws_size,
                              hipStream_t stream) {
    const float* actions = (const float*)d_in[0];
    const int* exps = (const int*)d_in[1];
    float* out = (float*)d_out;

    long long in0 = in_sizes[0];   // B*D
    long long in1 = in_sizes[1];   // D*NB
    long long osz = out_size;      // B*NB

    int D = (int)(sqrt((double)in0 * (double)in1 / (double)osz) + 0.5);
    if (D < 1) D = 1;
    int NB = (int)(in1 / D);
    int B = (int)(in0 / D);

    bool fast = (D == 8 && NB == 495 &&
                 (long long)B * NB == osz && (long long)B * D == in0 &&
                 (B % TILE) == 0);

    if (fast) {
        legendre_fast<<<B / TILE, THREADS, 0, stream>>>(actions, exps, out);
    } else {
        long long total = osz;
        long long want = (total + 255) / 256;
        int nblk = (want > 8192) ? 8192 : (int)(want > 0 ? want : 1);
        legendre_generic<<<nblk, 256, 0, stream>>>(
            actions, exps, out, total, D, NB);
    }
}